// Round 3
// baseline (8122.531 us; speedup 1.0000x reference)
//
#include <hip/hip_runtime.h>

typedef unsigned short u16;
typedef unsigned int   u32;

__device__ __forceinline__ float bflo(u32 u){ return __uint_as_float(u << 16); }
__device__ __forceinline__ float bfhi(u32 u){ return __uint_as_float(u & 0xffff0000u); }
__device__ __forceinline__ u16 f2bf(float f){
  u32 u = __float_as_uint(f);
  u32 r = (u + 0x7fffu + ((u >> 16) & 1u)) >> 16;
  return (u16)r;
}
__device__ __forceinline__ float lrn_one(float v, float pv){
  float avg = 0.5f*(v*v + pv*pv);
  float d = 1.0f + 2e-5f*avg;
  return v * exp2f(-0.75f * log2f(d));   // d >= 1, safe
}

// ---------------- K1: conv 7x7, 1->64, SAME pad 3, relu. x (2,1,128,128) f32 -> out (2,64,128,128) f32
__global__ __launch_bounds__(256) void k1_conv7x7(const float* __restrict__ x, const float* __restrict__ w1,
                                                  const float* __restrict__ b1, float* __restrict__ out){
  int idx = blockIdx.x*256 + threadIdx.x;          // 2*64*128*128 = 2097152
  int ox = idx & 127, oy = (idx>>7)&127, oc = (idx>>14)&63, n = idx>>20;
  float acc = b1[oc];
  const float* wb = w1 + oc*49;
  const float* xb = x + n*16384;
  #pragma unroll
  for (int ky=0;ky<7;++ky){
    int y = oy + ky - 3;
    if ((unsigned)y < 128u){
      #pragma unroll
      for (int kx=0;kx<7;++kx){
        int xx = ox + kx - 3;
        if ((unsigned)xx < 128u)
          acc += wb[ky*7+kx] * xb[y*128+xx];
      }
    }
  }
  out[idx] = acc > 0.f ? acc : 0.f;
}

// ---------------- K2: conv 5x5, 64->64, SAME pad 2, relu. (2,64,128,128) f32
__global__ __launch_bounds__(256) void k2_conv5x5(const float* __restrict__ in, const float* __restrict__ w2,
                                                  const float* __restrict__ b2, float* __restrict__ out){
  __shared__ float t[400];
  __shared__ float wl[25];
  int bid = blockIdx.x;                            // 8tx * 8ty * 64oc * 2n = 8192
  int tx = bid & 7, ty = (bid>>3)&7, oc = (bid>>6)&63, n = bid>>12;
  int tid = threadIdx.x;
  int oy0 = ty*16, ox0 = tx*16;
  int r = tid>>4, c = tid&15;
  float acc = 0.f;
  for (int ic=0; ic<64; ++ic){
    __syncthreads();
    for (int u=tid; u<400; u+=256){
      int rr=u/20, cc=u-rr*20;
      int gy = oy0+rr-2, gx = ox0+cc-2;
      t[u] = ((unsigned)gy<128u && (unsigned)gx<128u) ? in[((n*64+ic)*128+gy)*128+gx] : 0.f;
    }
    if (tid < 25) wl[tid] = w2[(oc*64+ic)*25 + tid];
    __syncthreads();
    #pragma unroll
    for (int ky=0;ky<5;++ky)
      #pragma unroll
      for (int kx=0;kx<5;++kx)
        acc += wl[ky*5+kx] * t[(r+ky)*20 + (c+kx)];
  }
  acc += b2[oc];
  out[((n*64+oc)*128 + oy0+r)*128 + ox0+c] = acc>0.f?acc:0.f;
}

// ---------------- K3: LRN(size2) + 4-crop + 2x2 maxpool. in (2,64,128,128) -> out (8,64,63,63)
__global__ __launch_bounds__(256) void k3_lrn_crop_pool(const float* __restrict__ h, float* __restrict__ out){
  int idx = blockIdx.x*256 + threadIdx.x;          // 8*64*63*63 = 2032128
  int j = idx % 63; int t1 = idx / 63;
  int i = t1 % 63; int t2 = t1 / 63;
  int c = t2 & 63; int b = t2 >> 6;
  int v = b >> 1, n = b & 1;                       // crops concat: batch' = v*2+n
  int r0 = v & 1, c0 = v >> 1;                     // v0:(0,0) v1:(1,0) v2:(0,1) v3:(1,1)
  const float* base  = h + ((n*64+c  )*128)*128;
  const float* basep = h + ((n*64+c-1)*128)*128;
  float m = -3.4e38f;
  #pragma unroll
  for (int a=0;a<2;++a)
    #pragma unroll
    for (int bb=0;bb<2;++bb){
      int y = r0+2*i+a, xx = c0+2*j+bb;
      float val = base[y*128+xx];
      float pv  = c ? basep[y*128+xx] : 0.f;
      m = fmaxf(m, lrn_one(val, pv));
    }
  out[idx] = m;
}

// ---------------- K4/K5: conv 3x3, 64->64, SAME pad 1, relu. (8,64,63,63) f32
__global__ __launch_bounds__(256) void k_conv3x3(const float* __restrict__ in, const float* __restrict__ w,
                                                 const float* __restrict__ bias, float* __restrict__ out){
  __shared__ float t[324];
  __shared__ float wl[9];
  int bid = blockIdx.x;                            // 4tx*4ty*64oc*8b = 8192
  int tx = bid & 3, ty = (bid>>2)&3, oc = (bid>>4)&63, b = bid>>10;
  int tid = threadIdx.x;
  int oy0 = ty*16, ox0 = tx*16;
  int r = tid>>4, c = tid&15;
  float acc = 0.f;
  for (int ic=0; ic<64; ++ic){
    __syncthreads();
    for (int u=tid; u<324; u+=256){
      int rr=u/18, cc=u-rr*18;
      int gy=oy0+rr-1, gx=ox0+cc-1;
      t[u] = ((unsigned)gy<63u && (unsigned)gx<63u) ? in[((b*64+ic)*63+gy)*63+gx] : 0.f;
    }
    if (tid<9) wl[tid] = w[(oc*64+ic)*9+tid];
    __syncthreads();
    #pragma unroll
    for (int ky=0;ky<3;++ky)
      #pragma unroll
      for (int kx=0;kx<3;++kx)
        acc += wl[ky*3+kx]*t[(r+ky)*18 + c+kx];
  }
  int oy = oy0+r, ox = ox0+c;
  if (oy<63 && ox<63){
    acc += bias[oc];
    out[((b*64+oc)*63+oy)*63+ox] = acc>0.f?acc:0.f;
  }
}

// ---------------- K6: LRN(size2) elementwise. (8,64,63,63)
__global__ __launch_bounds__(256) void k6_lrn(const float* __restrict__ in, float* __restrict__ out){
  int idx = blockIdx.x*256+threadIdx.x;            // 2032128
  int t2 = idx / 3969;                             // 3969 = 63*63
  int c = t2 & 63;
  float v  = in[idx];
  float pv = c ? in[idx - 3969] : 0.f;
  out[idx] = lrn_one(v, pv);
}

// ---------------- K7: conv 16x16 VALID, 64->1024, relu. in (8,64,63,63) f32 -> out (8,1024,48,48) bf16
// grid: 32 ocb * 6 oyg * 8 n = 1536 blocks. block: 32 oc x (8 rows x 48 cols). thread: 4 oc x 12 px.
__global__ __launch_bounds__(256) void k7_conv16(const float* __restrict__ in, const float* __restrict__ w5,
                                                 const float* __restrict__ b5, u16* __restrict__ out){
  __shared__ float ilds[1449];                      // 23 rows x 63 cols (contiguous rows in global)
  __shared__ __align__(16) float wlds[8320];        // 32 oc x 256 taps, row stride 260 (2-way bank alias: free)
  int bid = blockIdx.x;
  int ocb = bid & 31;
  int oyg = (bid >> 5) % 6;
  int n   = bid / 192;
  int tid = threadIdx.x;
  int to = tid & 7, tp = tid >> 3;
  int pgrow = tp >> 2, col0 = (tp & 3) * 12;
  int oy0 = oyg * 8;
  int oc0 = ocb * 32;
  float acc[4][12];
  #pragma unroll
  for (int q=0;q<4;++q)
    #pragma unroll
    for (int p=0;p<12;++p) acc[q][p]=0.f;
  #pragma unroll 1
  for (int ic=0; ic<64; ++ic){
    __syncthreads();
    const float* ibase = in + ((size_t)(n*64+ic)*63 + oy0)*63;
    for (int u=tid; u<1449; u+=256) ilds[u] = ibase[u];
    for (int u=tid; u<2048; u+=256){                // 32 oc x 64 float4 each
      int oc_l = u >> 6, rem = u & 63;
      const float4* src = (const float4*)(w5 + ((size_t)(oc0+oc_l)*64 + ic)*256);
      *((float4*)&wlds[oc_l*260 + rem*4]) = src[rem];
    }
    __syncthreads();
    #pragma unroll 1
    for (int ky=0; ky<16; ++ky){
      const float* row = ilds + (pgrow+ky)*63 + col0;
      float f[27];
      #pragma unroll
      for (int u2=0;u2<27;++u2) f[u2] = row[u2];
      #pragma unroll
      for (int q=0;q<4;++q){
        const float4* wr = (const float4*)&wlds[(to*4+q)*260 + ky*16];
        float4 wa = wr[0], wb = wr[1], wc = wr[2], wd = wr[3];
        float wv[16] = {wa.x,wa.y,wa.z,wa.w, wb.x,wb.y,wb.z,wb.w,
                        wc.x,wc.y,wc.z,wc.w, wd.x,wd.y,wd.z,wd.w};
        #pragma unroll
        for (int kx=0;kx<16;++kx)
          #pragma unroll
          for (int p=0;p<12;++p)
            acc[q][p] += wv[kx]*f[kx+p];
      }
    }
  }
  #pragma unroll
  for (int q=0;q<4;++q){
    int oc = oc0 + to*4 + q;
    float bias = b5[oc];
    int row = oy0 + pgrow;
    #pragma unroll
    for (int p=0;p<12;++p){
      float vv = acc[q][p] + bias;
      vv = vv>0.f?vv:0.f;
      out[(((size_t)n*1024+oc)*48+row)*48 + col0+p] = f2bf(vv);
    }
  }
}

// ---------------- K8: fused 1x1 conv (1024->1024, relu) + 1x1 conv (1024->1) + sigmoid + interweave
// grid: 8 bprime * 48 rows * 3 colgroups = 1152 blocks. block: 16 px; thread: 4 oc (x16 px).
// OUTPUT IS FP32 (2,1,96,96).
__global__ __launch_bounds__(256) void k8_head(const u16* __restrict__ y5, const float* __restrict__ w6,
                                               const float* __restrict__ b6, const float* __restrict__ w7,
                                               const float* __restrict__ b7, float* __restrict__ out){
  __shared__ __align__(16) u16 xv[16][1024];       // 32 KiB
  __shared__ float red[16][256];                   // 16 KiB
  int bid = blockIdx.x;
  int pg = bid % 144;  int bprime = bid / 144;
  int i = pg / 3;      int col0 = (pg % 3) * 16;
  int tid = threadIdx.x;
  for (int u=tid; u<16384; u+=256){
    int ic = u >> 4, p = u & 15;
    xv[p][ic] = y5[(((size_t)bprime*1024 + ic)*48 + i)*48 + col0 + p];
  }
  __syncthreads();
  float dot[4][16];
  #pragma unroll
  for (int q=0;q<4;++q)
    #pragma unroll
    for (int p=0;p<16;++p) dot[q][p]=0.f;
  #pragma unroll 1
  for (int icb=0; icb<128; ++icb){
    float wf[4][8];
    #pragma unroll
    for (int q=0;q<4;++q){
      const float4* wp = (const float4*)(w6 + (size_t)(tid*4+q)*1024 + icb*8);
      float4 a = wp[0], b = wp[1];
      wf[q][0]=a.x; wf[q][1]=a.y; wf[q][2]=a.z; wf[q][3]=a.w;
      wf[q][4]=b.x; wf[q][5]=b.y; wf[q][6]=b.z; wf[q][7]=b.w;
    }
    #pragma unroll
    for (int p=0;p<16;++p){
      uint4 xu = *((const uint4*)&xv[p][icb*8]);   // broadcast read (uniform p): conflict-free
      float xf[8];
      xf[0]=bflo(xu.x); xf[1]=bfhi(xu.x); xf[2]=bflo(xu.y); xf[3]=bfhi(xu.y);
      xf[4]=bflo(xu.z); xf[5]=bfhi(xu.z); xf[6]=bflo(xu.w); xf[7]=bfhi(xu.w);
      #pragma unroll
      for (int q=0;q<4;++q)
        #pragma unroll
        for (int u8=0;u8<8;++u8)
          dot[q][p] += wf[q][u8]*xf[u8];
    }
  }
  float part[16];
  #pragma unroll
  for (int p=0;p<16;++p) part[p]=0.f;
  #pragma unroll
  for (int q=0;q<4;++q){
    int oc = tid*4+q;
    float bb  = b6[oc];
    float w7v = w7[oc];
    #pragma unroll
    for (int p=0;p<16;++p){
      float z = dot[q][p] + bb; z = z>0.f?z:0.f;
      part[p] += w7v * z;
    }
  }
  #pragma unroll
  for (int p=0;p<16;++p) red[p][tid]=part[p];
  __syncthreads();
  for (int s=128; s>0; s>>=1){
    if (tid < s){
      #pragma unroll
      for (int p=0;p<16;++p) red[p][tid] += red[p][tid+s];
    }
    __syncthreads();
  }
  if (tid < 16){
    int p = tid;
    float s = red[p][0] + b7[0];
    float sig = 1.f / (1.f + expf(-s));
    int v = bprime >> 1, n = bprime & 1;
    int a = v & 1, bcol = v >> 1;
    int orow = 2*i + a, ocol = 2*(col0+p) + bcol;
    out[((size_t)n*96 + orow)*96 + ocol] = sig;
  }
}

// ---------------- workspace layout (fp32 element offsets)
// C at 0 (2,032,128 f32, slot 2,097,152) — pooled / y4_lrn
// A at 2,097,152 ; B at 4,194,304 (each 2,097,152 f32) — dead after k6
// F = bf16 y5 (18,874,368 u16) overlaps A+B region (live only k7->k8)
// peak ws bytes: 46,137,344

extern "C" void kernel_launch(void* const* d_in, const int* in_sizes, int n_in,
                              void* d_out, int out_size, void* d_ws, size_t ws_size,
                              hipStream_t stream){
  const float* x  = (const float*)d_in[0];
  const float* w1 = (const float*)d_in[1];
  const float* b1 = (const float*)d_in[2];
  const float* w2 = (const float*)d_in[3];
  const float* b2 = (const float*)d_in[4];
  const float* w3 = (const float*)d_in[5];
  const float* b3 = (const float*)d_in[6];
  const float* w4 = (const float*)d_in[7];
  const float* b4 = (const float*)d_in[8];
  const float* w5 = (const float*)d_in[9];
  const float* b5 = (const float*)d_in[10];
  const float* w6 = (const float*)d_in[11];
  const float* b6 = (const float*)d_in[12];
  const float* w7 = (const float*)d_in[13];
  const float* b7 = (const float*)d_in[14];
  float* ws = (float*)d_ws;
  float* C = ws;
  float* A = ws + 2097152;
  float* B = ws + 4194304;
  u16*   F = (u16*)(ws + 2097152);
  float* out = (float*)d_out;

  hipLaunchKernelGGL(k1_conv7x7,      dim3(8192), dim3(256), 0, stream, x, w1, b1, A);
  hipLaunchKernelGGL(k2_conv5x5,      dim3(8192), dim3(256), 0, stream, A, w2, b2, B);
  hipLaunchKernelGGL(k3_lrn_crop_pool,dim3(7938), dim3(256), 0, stream, B, C);
  hipLaunchKernelGGL(k_conv3x3,       dim3(8192), dim3(256), 0, stream, C, w3, b3, A);
  hipLaunchKernelGGL(k_conv3x3,       dim3(8192), dim3(256), 0, stream, A, w4, b4, B);
  hipLaunchKernelGGL(k6_lrn,          dim3(7938), dim3(256), 0, stream, B, C);
  hipLaunchKernelGGL(k7_conv16,       dim3(1536), dim3(256), 0, stream, C, w5, b5, F);
  hipLaunchKernelGGL(k8_head,         dim3(1152), dim3(256), 0, stream, F, w6, b6, w7, b7, out);
}

// Round 4
// 2726.282 us; speedup vs baseline: 2.9793x; 2.9793x over previous
//
#include <hip/hip_runtime.h>

typedef unsigned short u16;
typedef unsigned int   u32;
typedef short short8 __attribute__((ext_vector_type(8)));
typedef float f32x4  __attribute__((ext_vector_type(4)));

__device__ __forceinline__ float bflo(u32 u){ return __uint_as_float(u << 16); }
__device__ __forceinline__ float bfhi(u32 u){ return __uint_as_float(u & 0xffff0000u); }
__device__ __forceinline__ u16 f2bf(float f){
  u32 u = __float_as_uint(f);
  u32 r = (u + 0x7fffu + ((u >> 16) & 1u)) >> 16;
  return (u16)r;
}
__device__ __forceinline__ float lrn_one(float v, float pv){
  float avg = 0.5f*(v*v + pv*pv);
  float d = 1.0f + 2e-5f*avg;
  return v * exp2f(-0.75f * log2f(d));   // d >= 1, safe
}

// ---------------- K0a: prepack w5 fp32 [1024][64][16][16] -> bf16 fragment order
// Wpk5[ocb(8)][chunk(32)][kx(16)][quad(4)][oc128(128)][j(8)]
__global__ __launch_bounds__(256) void k0w5(const float* __restrict__ w5, u16* __restrict__ wpk){
  int idx = blockIdx.x*256 + threadIdx.x;            // 16,777,216
  int j     =  idx        & 7;
  int oc128 = (idx >> 3)  & 127;
  int quad  = (idx >> 10) & 3;
  int kx    = (idx >> 12) & 15;
  int chunk = (idx >> 16) & 31;
  int ocb   =  idx >> 21;
  int oc = ocb*128 + oc128;
  int ic = chunk*2 + (quad>>1);
  int ky = (quad&1)*8 + j;
  wpk[idx] = f2bf(w5[((oc*64 + ic)*16 + ky)*16 + kx]);
}

// ---------------- K0b: prepack w6 fp32[1024][1024] -> bf16 same layout
__global__ __launch_bounds__(256) void k0w6(const float* __restrict__ w6, u16* __restrict__ wpk){
  int idx = blockIdx.x*256 + threadIdx.x;            // 1,048,576
  wpk[idx] = f2bf(w6[idx]);
}

// ---------------- K0c: zero the k8 accumulation buffer (18432 f32)
__global__ __launch_bounds__(256) void k0z(float* __restrict__ accum){
  int idx = blockIdx.x*256 + threadIdx.x;
  if (idx < 18432) accum[idx] = 0.f;
}

// ---------------- K1: conv 7x7, 1->64, SAME pad 3, relu
__global__ __launch_bounds__(256) void k1_conv7x7(const float* __restrict__ x, const float* __restrict__ w1,
                                                  const float* __restrict__ b1, float* __restrict__ out){
  int idx = blockIdx.x*256 + threadIdx.x;            // 2,097,152
  int ox = idx & 127, oy = (idx>>7)&127, oc = (idx>>14)&63, n = idx>>20;
  float acc = b1[oc];
  const float* wb = w1 + oc*49;
  const float* xb = x + n*16384;
  #pragma unroll
  for (int ky=0;ky<7;++ky){
    int y = oy + ky - 3;
    if ((unsigned)y < 128u){
      #pragma unroll
      for (int kx=0;kx<7;++kx){
        int xx = ox + kx - 3;
        if ((unsigned)xx < 128u)
          acc += wb[ky*7+kx] * xb[y*128+xx];
      }
    }
  }
  out[idx] = acc > 0.f ? acc : 0.f;
}

// ---------------- K2: conv 5x5, 64->64, SAME pad 2, relu
__global__ __launch_bounds__(256) void k2_conv5x5(const float* __restrict__ in, const float* __restrict__ w2,
                                                  const float* __restrict__ b2, float* __restrict__ out){
  __shared__ float t[400];
  __shared__ float wl[25];
  int bid = blockIdx.x;                              // 8192
  int tx = bid & 7, ty = (bid>>3)&7, oc = (bid>>6)&63, n = bid>>12;
  int tid = threadIdx.x;
  int oy0 = ty*16, ox0 = tx*16;
  int r = tid>>4, c = tid&15;
  float acc = 0.f;
  for (int ic=0; ic<64; ++ic){
    __syncthreads();
    for (int u=tid; u<400; u+=256){
      int rr=u/20, cc=u-rr*20;
      int gy = oy0+rr-2, gx = ox0+cc-2;
      t[u] = ((unsigned)gy<128u && (unsigned)gx<128u) ? in[((n*64+ic)*128+gy)*128+gx] : 0.f;
    }
    if (tid < 25) wl[tid] = w2[(oc*64+ic)*25 + tid];
    __syncthreads();
    #pragma unroll
    for (int ky=0;ky<5;++ky)
      #pragma unroll
      for (int kx=0;kx<5;++kx)
        acc += wl[ky*5+kx] * t[(r+ky)*20 + (c+kx)];
  }
  acc += b2[oc];
  out[((n*64+oc)*128 + oy0+r)*128 + ox0+c] = acc>0.f?acc:0.f;
}

// ---------------- K3: LRN + 4-crop + 2x2 maxpool
__global__ __launch_bounds__(256) void k3_lrn_crop_pool(const float* __restrict__ h, float* __restrict__ out){
  int idx = blockIdx.x*256 + threadIdx.x;            // 2,032,128
  int j = idx % 63; int t1 = idx / 63;
  int i = t1 % 63; int t2 = t1 / 63;
  int c = t2 & 63; int b = t2 >> 6;
  int v = b >> 1, n = b & 1;
  int r0 = v & 1, c0 = v >> 1;
  const float* base  = h + ((n*64+c  )*128)*128;
  const float* basep = h + ((n*64+c-1)*128)*128;
  float m = -3.4e38f;
  #pragma unroll
  for (int a=0;a<2;++a)
    #pragma unroll
    for (int bb=0;bb<2;++bb){
      int y = r0+2*i+a, xx = c0+2*j+bb;
      float val = base[y*128+xx];
      float pv  = c ? basep[y*128+xx] : 0.f;
      m = fmaxf(m, lrn_one(val, pv));
    }
  out[idx] = m;
}

// ---------------- K4/K5: conv 3x3, 64->64, SAME pad 1, relu
__global__ __launch_bounds__(256) void k_conv3x3(const float* __restrict__ in, const float* __restrict__ w,
                                                 const float* __restrict__ bias, float* __restrict__ out){
  __shared__ float t[324];
  __shared__ float wl[9];
  int bid = blockIdx.x;                              // 8192
  int tx = bid & 3, ty = (bid>>2)&3, oc = (bid>>4)&63, b = bid>>10;
  int tid = threadIdx.x;
  int oy0 = ty*16, ox0 = tx*16;
  int r = tid>>4, c = tid&15;
  float acc = 0.f;
  for (int ic=0; ic<64; ++ic){
    __syncthreads();
    for (int u=tid; u<324; u+=256){
      int rr=u/18, cc=u-rr*18;
      int gy=oy0+rr-1, gx=ox0+cc-1;
      t[u] = ((unsigned)gy<63u && (unsigned)gx<63u) ? in[((b*64+ic)*63+gy)*63+gx] : 0.f;
    }
    if (tid<9) wl[tid] = w[(oc*64+ic)*9+tid];
    __syncthreads();
    #pragma unroll
    for (int ky=0;ky<3;++ky)
      #pragma unroll
      for (int kx=0;kx<3;++kx)
        acc += wl[ky*3+kx]*t[(r+ky)*18 + c+kx];
  }
  int oy = oy0+r, ox = ox0+c;
  if (oy<63 && ox<63){
    acc += bias[oc];
    out[((b*64+oc)*63+oy)*63+ox] = acc>0.f?acc:0.f;
  }
}

// ---------------- K6: LRN elementwise
__global__ __launch_bounds__(256) void k6_lrn(const float* __restrict__ in, float* __restrict__ out){
  int idx = blockIdx.x*256+threadIdx.x;              // 2,032,128
  int t2 = idx / 3969;
  int c = t2 & 63;
  float v  = in[idx];
  float pv = c ? in[idx - 3969] : 0.f;
  out[idx] = lrn_one(v, pv);
}

// ---------------- K7m: conv 16x16 VALID via MFMA implicit GEMM.
// in (8,64,63,63) f32 -> out y5 (8,1024,48,48) bf16
// grid 1536 = [ocb 8 (bid&7, XCD swizzle)][n8 8][rowgroup 24]; block 128 thr = 2 waves.
// block tile: 128 oc x 96 px (output rows {b, b+8}, all 48 cols).
// wave tile: 64 oc x 96 px = 4 m-tiles x 6 n-tiles of mfma_f32_16x16x32_bf16.
// K decomposition: per kx (16 taps), K=(ic,ky) chunked by 2 ic (K_c=32).
__global__ __launch_bounds__(128) void k7m(const float* __restrict__ in, const u16* __restrict__ wpk,
                                           const float* __restrict__ b5, u16* __restrict__ y5){
  __shared__ __align__(16) u16 itile[5040];          // [ic2(2)][col(63)][iy slot 40] col-major: 10,080 B
  int bid = blockIdx.x;
  int ocb = bid & 7;
  int r   = bid >> 3;
  int n8  = r & 7;
  int g   = r >> 3;                                  // 0..23
  int brow = (g>>3)*16 + (g&7);                      // {0..7,16..23,32..39}; rows {brow, brow+8}
  int tid = threadIdx.x;
  int w = tid >> 6, lane = tid & 63, quad = lane >> 4, m = lane & 15;

  f32x4 acc[4][6];
  #pragma unroll
  for (int tm=0;tm<4;++tm)
    #pragma unroll
    for (int t=0;t<6;++t) acc[tm][t] = (f32x4){0.f,0.f,0.f,0.f};

  const u16* wblock = wpk + ((size_t)(ocb*32) << 16);  // ocb*32 chunks * 16 kx * 4096

  #pragma unroll 1
  for (int chunk=0; chunk<32; ++chunk){
    int ic0 = chunk*2;
    __syncthreads();
    for (int u=tid; u<3024; u+=128){                 // 2 ic x 24 rows x 63 cols
      int col = u % 63; int t = u / 63;              // t < 48
      int iy = t % 24;  int ic2 = t / 24;
      float v = in[((size_t)(n8*64 + ic0 + ic2)*63 + brow + iy)*63 + col];
      itile[(ic2*63 + col)*40 + iy] = f2bf(v);
    }
    __syncthreads();
    const u16* wchunk = wblock + ((size_t)chunk << 16);  // chunk*16*4096
    #pragma unroll 1
    for (int kx=0; kx<16; ++kx){
      short8 af[4];
      #pragma unroll
      for (int tm=0;tm<4;++tm)
        af[tm] = *(const short8*)(wchunk + kx*4096 + quad*1024 + (w*64 + tm*16 + m)*8);
      short8 bf[6];
      #pragma unroll
      for (int t=0;t<6;++t){
        int col = (t%3)*16 + m + kx;                 // <= 62
        int off = ((quad>>1)*63 + col)*40 + ((t>=3)?8:0) + (quad&1)*8;
        bf[t] = *(const short8*)(itile + off);       // 16B aligned
      }
      #pragma unroll
      for (int tm=0;tm<4;++tm)
        #pragma unroll
        for (int t=0;t<6;++t)
          acc[tm][t] = __builtin_amdgcn_mfma_f32_16x16x32_bf16(af[tm], bf[t], acc[tm][t], 0, 0, 0);
    }
  }
  // epilogue: oc = ocb*128 + w*64 + tm*16 + quad*4 + rr ; px: col=lane&15
  #pragma unroll
  for (int tm=0;tm<4;++tm){
    #pragma unroll
    for (int rr=0;rr<4;++rr){
      int oc = ocb*128 + w*64 + tm*16 + quad*4 + rr;
      float bias = b5[oc];
      #pragma unroll
      for (int t=0;t<6;++t){
        int oy = brow + ((t>=3)?8:0);
        int ox = (t%3)*16 + m;
        float v = acc[tm][t][rr] + bias;
        v = v>0.f ? v : 0.f;
        y5[(((size_t)n8*1024 + oc)*48 + oy)*48 + ox] = f2bf(v);
      }
    }
  }
}

// ---------------- K8a: 1x1 conv (1024->1024) MFMA + relu + w7-dot + block reduce + atomicAdd
// grid 1536 = [mb 8 (bid&7)][n8 8][rowpair 24]; block 128 thr = 2 waves.
// block tile: 128 oc x 96 px (2 consecutive rows). wave: 64 oc x 96 px.
__global__ __launch_bounds__(128) void k8a(const u16* __restrict__ y5, const u16* __restrict__ w6pk,
                                           const float* __restrict__ b6, const float* __restrict__ w7,
                                           float* __restrict__ accum){
  __shared__ __align__(16) u16 btile[96*136];        // [pxl(96)][ic2 slot 136] : 26,112 B
  __shared__ float red[8*96];
  int bid = blockIdx.x;
  int mb = bid & 7;
  int r  = bid >> 3;
  int n8 = r / 24, rp = r % 24;
  int r0 = 2*rp;
  int tid = threadIdx.x;
  int w = tid >> 6, lane = tid & 63, quad = lane >> 4, m = lane & 15;

  f32x4 acc[4][6];
  #pragma unroll
  for (int tm=0;tm<4;++tm)
    #pragma unroll
    for (int t=0;t<6;++t) acc[tm][t] = (f32x4){0.f,0.f,0.f,0.f};

  #pragma unroll 1
  for (int kc=0; kc<8; ++kc){
    __syncthreads();
    for (int u=tid; u<6144; u+=128){                 // 128 ic x 48 px-pairs
      int pp = u % 48; int ic2 = u / 48;
      int rowl = pp / 24; int ox0 = (pp % 24)*2;
      u32 val = *(const u32*)(y5 + (((size_t)(n8*1024 + kc*128 + ic2)*48) + r0 + rowl)*48 + ox0);
      int px = rowl*48 + ox0;
      btile[(px  )*136 + ic2] = (u16)(val & 0xffffu);
      btile[(px+1)*136 + ic2] = (u16)(val >> 16);
    }
    __syncthreads();
    #pragma unroll 1
    for (int kk=0; kk<4; ++kk){
      short8 af[4];
      #pragma unroll
      for (int tm=0;tm<4;++tm)
        af[tm] = *(const short8*)(w6pk + (size_t)(mb*128 + w*64 + tm*16 + m)*1024 + kc*128 + kk*32 + quad*8);
      short8 bf[6];
      #pragma unroll
      for (int t=0;t<6;++t){
        int pxl = ((t>=3)?48:0) + (t%3)*16 + m;
        bf[t] = *(const short8*)(btile + pxl*136 + kk*32 + quad*8);   // 272B px stride: 16B aligned
      }
      #pragma unroll
      for (int tm=0;tm<4;++tm)
        #pragma unroll
        for (int t=0;t<6;++t)
          acc[tm][t] = __builtin_amdgcn_mfma_f32_16x16x32_bf16(af[tm], bf[t], acc[tm][t], 0, 0, 0);
    }
  }
  // fold: z = relu(acc + b6[oc]); partial[px] += w7[oc]*z over this lane's ocs
  float part[6];
  #pragma unroll
  for (int t=0;t<6;++t) part[t]=0.f;
  #pragma unroll
  for (int tm=0;tm<4;++tm){
    #pragma unroll
    for (int rr=0;rr<4;++rr){
      int oc = mb*128 + w*64 + tm*16 + quad*4 + rr;
      float bb = b6[oc];
      float ww = w7[oc];
      #pragma unroll
      for (int t=0;t<6;++t){
        float z = acc[tm][t][rr] + bb;
        z = z>0.f ? z : 0.f;
        part[t] += ww*z;
      }
    }
  }
  #pragma unroll
  for (int t=0;t<6;++t){
    int pxl = ((t>=3)?48:0) + (t%3)*16 + m;
    red[(w*4+quad)*96 + pxl] = part[t];
  }
  __syncthreads();
  if (tid < 96){
    float s = 0.f;
    #pragma unroll
    for (int k=0;k<8;++k) s += red[k*96 + tid];
    int rowl = tid / 48, ox = tid % 48;
    atomicAdd(&accum[((size_t)n8*48 + r0 + rowl)*48 + ox], s);
  }
}

// ---------------- K8b: sigmoid + interweave. accum (8,48,48) -> out (2,1,96,96) f32
__global__ __launch_bounds__(256) void k8b(const float* __restrict__ accum, const float* __restrict__ b7,
                                           float* __restrict__ out){
  int idx = blockIdx.x*256 + threadIdx.x;
  if (idx >= 18432) return;
  int n8 = idx / 2304; int rem = idx % 2304;
  int oy = rem / 48, ox = rem % 48;
  float s = accum[idx] + b7[0];
  float sig = 1.f / (1.f + expf(-s));
  int v = n8 >> 1, n = n8 & 1;
  int a = v & 1, bcol = v >> 1;
  out[((size_t)n*96 + 2*oy + a)*96 + 2*ox + bcol] = sig;
}

// ---------------- workspace layout (fp32-element offsets)
// C    [0,         2,097,152)  conv inputs/outputs chain
// A    [2,097,152, 4,194,304)  dead after k6
// B    [4,194,304, 6,291,456)  dead after k6
// F    [2,097,152, 11,534,336) y5 bf16 (overlaps dead A,B; live k7m->k8a)
// Wpk5 [11,534,336, 19,922,944) bf16 16,777,216
// W6pk [19,922,944, 20,447,232) bf16 1,048,576
// accum[20,447,232, 20,465,664) f32 18,432
// total ~81.9 MB

extern "C" void kernel_launch(void* const* d_in, const int* in_sizes, int n_in,
                              void* d_out, int out_size, void* d_ws, size_t ws_size,
                              hipStream_t stream){
  const float* x  = (const float*)d_in[0];
  const float* w1 = (const float*)d_in[1];
  const float* b1 = (const float*)d_in[2];
  const float* w2 = (const float*)d_in[3];
  const float* b2 = (const float*)d_in[4];
  const float* w3 = (const float*)d_in[5];
  const float* b3 = (const float*)d_in[6];
  const float* w4 = (const float*)d_in[7];
  const float* b4 = (const float*)d_in[8];
  const float* w5 = (const float*)d_in[9];
  const float* b5 = (const float*)d_in[10];
  const float* w6 = (const float*)d_in[11];
  const float* b6 = (const float*)d_in[12];
  const float* w7 = (const float*)d_in[13];
  const float* b7 = (const float*)d_in[14];
  float* ws = (float*)d_ws;
  float* C = ws;
  float* A = ws + 2097152;
  float* B = ws + 4194304;
  u16*   F    = (u16*)(ws + 2097152);
  u16*   Wpk5 = (u16*)(ws + 11534336);
  u16*   W6pk = (u16*)(ws + 19922944);
  float* accum = ws + 20447232;
  float* out = (float*)d_out;

  hipLaunchKernelGGL(k0w5,            dim3(65536), dim3(256), 0, stream, w5, Wpk5);
  hipLaunchKernelGGL(k0w6,            dim3(4096),  dim3(256), 0, stream, w6, W6pk);
  hipLaunchKernelGGL(k0z,             dim3(72),    dim3(256), 0, stream, accum);
  hipLaunchKernelGGL(k1_conv7x7,      dim3(8192),  dim3(256), 0, stream, x, w1, b1, A);
  hipLaunchKernelGGL(k2_conv5x5,      dim3(8192),  dim3(256), 0, stream, A, w2, b2, B);
  hipLaunchKernelGGL(k3_lrn_crop_pool,dim3(7938),  dim3(256), 0, stream, B, C);
  hipLaunchKernelGGL(k_conv3x3,       dim3(8192),  dim3(256), 0, stream, C, w3, b3, A);
  hipLaunchKernelGGL(k_conv3x3,       dim3(8192),  dim3(256), 0, stream, A, w4, b4, B);
  hipLaunchKernelGGL(k6_lrn,          dim3(7938),  dim3(256), 0, stream, B, C);
  hipLaunchKernelGGL(k7m,             dim3(1536),  dim3(128), 0, stream, C, Wpk5, b5, F);
  hipLaunchKernelGGL(k8a,             dim3(1536),  dim3(128), 0, stream, F, W6pk, b6, w7, accum);
  hipLaunchKernelGGL(k8b,             dim3(72),    dim3(256), 0, stream, accum, b7, out);
}

// Round 5
// 2314.141 us; speedup vs baseline: 3.5100x; 1.1781x over previous
//
#include <hip/hip_runtime.h>

typedef unsigned short u16;
typedef unsigned int   u32;
typedef short short8 __attribute__((ext_vector_type(8)));
typedef float f32x4  __attribute__((ext_vector_type(4)));

__device__ __forceinline__ float bflo(u32 u){ return __uint_as_float(u << 16); }
__device__ __forceinline__ float bfhi(u32 u){ return __uint_as_float(u & 0xffff0000u); }
__device__ __forceinline__ u16 f2bf(float f){
  u32 u = __float_as_uint(f);
  u32 r = (u + 0x7fffu + ((u >> 16) & 1u)) >> 16;
  return (u16)r;
}
__device__ __forceinline__ float lrn_one(float v, float pv){
  float avg = 0.5f*(v*v + pv*pv);
  float d = 1.0f + 2e-5f*avg;
  return v * exp2f(-0.75f * log2f(d));   // d >= 1, safe
}

// ---------------- K0a: prepack w5 fp32 [1024][64][16][16] -> bf16 fragment order
// Wpk5[ocb(8)][chunk(32)][kx(16)][quad(4)][oc128(128)][j(8)]
__global__ __launch_bounds__(256) void k0w5(const float* __restrict__ w5, u16* __restrict__ wpk){
  int idx = blockIdx.x*256 + threadIdx.x;            // 16,777,216
  int j     =  idx        & 7;
  int oc128 = (idx >> 3)  & 127;
  int quad  = (idx >> 10) & 3;
  int kx    = (idx >> 12) & 15;
  int chunk = (idx >> 16) & 31;
  int ocb   =  idx >> 21;
  int oc = ocb*128 + oc128;
  int ic = chunk*2 + (quad>>1);
  int ky = (quad&1)*8 + j;
  wpk[idx] = f2bf(w5[((oc*64 + ic)*16 + ky)*16 + kx]);
}

// ---------------- K0b: prepack w6 fp32[1024][1024] -> bf16
__global__ __launch_bounds__(256) void k0w6(const float* __restrict__ w6, u16* __restrict__ wpk){
  int idx = blockIdx.x*256 + threadIdx.x;            // 1,048,576
  wpk[idx] = f2bf(w6[idx]);
}

// ---------------- K0c: zero the k8 accumulation buffer (18432 f32)
__global__ __launch_bounds__(256) void k0z(float* __restrict__ accum){
  int idx = blockIdx.x*256 + threadIdx.x;
  if (idx < 18432) accum[idx] = 0.f;
}

// ---------------- K1: conv 7x7, 1->64, SAME pad 3, relu
__global__ __launch_bounds__(256) void k1_conv7x7(const float* __restrict__ x, const float* __restrict__ w1,
                                                  const float* __restrict__ b1, float* __restrict__ out){
  int idx = blockIdx.x*256 + threadIdx.x;            // 2,097,152
  int ox = idx & 127, oy = (idx>>7)&127, oc = (idx>>14)&63, n = idx>>20;
  float acc = b1[oc];
  const float* wb = w1 + oc*49;
  const float* xb = x + n*16384;
  #pragma unroll
  for (int ky=0;ky<7;++ky){
    int y = oy + ky - 3;
    if ((unsigned)y < 128u){
      #pragma unroll
      for (int kx=0;kx<7;++kx){
        int xx = ox + kx - 3;
        if ((unsigned)xx < 128u)
          acc += wb[ky*7+kx] * xb[y*128+xx];
      }
    }
  }
  out[idx] = acc > 0.f ? acc : 0.f;
}

// ---------------- K2: conv 5x5, 64->64, SAME pad 2, relu
__global__ __launch_bounds__(256) void k2_conv5x5(const float* __restrict__ in, const float* __restrict__ w2,
                                                  const float* __restrict__ b2, float* __restrict__ out){
  __shared__ float t[400];
  __shared__ float wl[25];
  int bid = blockIdx.x;                              // 8192
  int tx = bid & 7, ty = (bid>>3)&7, oc = (bid>>6)&63, n = bid>>12;
  int tid = threadIdx.x;
  int oy0 = ty*16, ox0 = tx*16;
  int r = tid>>4, c = tid&15;
  float acc = 0.f;
  for (int ic=0; ic<64; ++ic){
    __syncthreads();
    for (int u=tid; u<400; u+=256){
      int rr=u/20, cc=u-rr*20;
      int gy = oy0+rr-2, gx = ox0+cc-2;
      t[u] = ((unsigned)gy<128u && (unsigned)gx<128u) ? in[((n*64+ic)*128+gy)*128+gx] : 0.f;
    }
    if (tid < 25) wl[tid] = w2[(oc*64+ic)*25 + tid];
    __syncthreads();
    #pragma unroll
    for (int ky=0;ky<5;++ky)
      #pragma unroll
      for (int kx=0;kx<5;++kx)
        acc += wl[ky*5+kx] * t[(r+ky)*20 + (c+kx)];
  }
  acc += b2[oc];
  out[((n*64+oc)*128 + oy0+r)*128 + ox0+c] = acc>0.f?acc:0.f;
}

// ---------------- K3: LRN + 4-crop + 2x2 maxpool
__global__ __launch_bounds__(256) void k3_lrn_crop_pool(const float* __restrict__ h, float* __restrict__ out){
  int idx = blockIdx.x*256 + threadIdx.x;            // 2,032,128
  int j = idx % 63; int t1 = idx / 63;
  int i = t1 % 63; int t2 = t1 / 63;
  int c = t2 & 63; int b = t2 >> 6;
  int v = b >> 1, n = b & 1;
  int r0 = v & 1, c0 = v >> 1;
  const float* base  = h + ((n*64+c  )*128)*128;
  const float* basep = h + ((n*64+c-1)*128)*128;
  float m = -3.4e38f;
  #pragma unroll
  for (int a=0;a<2;++a)
    #pragma unroll
    for (int bb=0;bb<2;++bb){
      int y = r0+2*i+a, xx = c0+2*j+bb;
      float val = base[y*128+xx];
      float pv  = c ? basep[y*128+xx] : 0.f;
      m = fmaxf(m, lrn_one(val, pv));
    }
  out[idx] = m;
}

// ---------------- K4/K5: conv 3x3, 64->64, SAME pad 1, relu
__global__ __launch_bounds__(256) void k_conv3x3(const float* __restrict__ in, const float* __restrict__ w,
                                                 const float* __restrict__ bias, float* __restrict__ out){
  __shared__ float t[324];
  __shared__ float wl[9];
  int bid = blockIdx.x;                              // 8192
  int tx = bid & 3, ty = (bid>>2)&3, oc = (bid>>4)&63, b = bid>>10;
  int tid = threadIdx.x;
  int oy0 = ty*16, ox0 = tx*16;
  int r = tid>>4, c = tid&15;
  float acc = 0.f;
  for (int ic=0; ic<64; ++ic){
    __syncthreads();
    for (int u=tid; u<324; u+=256){
      int rr=u/18, cc=u-rr*18;
      int gy=oy0+rr-1, gx=ox0+cc-1;
      t[u] = ((unsigned)gy<63u && (unsigned)gx<63u) ? in[((b*64+ic)*63+gy)*63+gx] : 0.f;
    }
    if (tid<9) wl[tid] = w[(oc*64+ic)*9+tid];
    __syncthreads();
    #pragma unroll
    for (int ky=0;ky<3;++ky)
      #pragma unroll
      for (int kx=0;kx<3;++kx)
        acc += wl[ky*3+kx]*t[(r+ky)*18 + c+kx];
  }
  int oy = oy0+r, ox = ox0+c;
  if (oy<63 && ox<63){
    acc += bias[oc];
    out[((b*64+oc)*63+oy)*63+ox] = acc>0.f?acc:0.f;
  }
}

// ---------------- K6: LRN elementwise, f32 (8,64,63,63) -> bf16 padded (8,64,64,64)
__global__ __launch_bounds__(256) void k6_lrn_bf(const float* __restrict__ in, u16* __restrict__ outb){
  int idx = blockIdx.x*256+threadIdx.x;              // 8*64*64*64 = 2,097,152
  int col = idx & 63, iy = (idx>>6)&63, ic = (idx>>12)&63, b = idx>>18;
  u16 o = 0;
  if (col < 63 && iy < 63){
    int src = ((b*64+ic)*63 + iy)*63 + col;
    float v  = in[src];
    float pv = ic ? in[src - 3969] : 0.f;
    o = f2bf(lrn_one(v, pv));
  }
  outb[idx] = o;
}

// ---------------- K7m v2: conv 16x16 VALID via MFMA implicit GEMM.
// in bf16 padded (8,64,64,64) -> y5 (8,1024,48,48) bf16
// grid 512 = [ocb 8 = bid&7 (XCD-pinned)][n8 8][r 8]; block 192 thr = 3 waves.
// block tile: 128 oc x 288 px (rows r, r+8, ..., r+40; all 48 cols).
// wave w: 128 oc (tm=8) x 96 px (rows {r+16w, r+16w+8} x 48 cols, nt=6).
// LDS itile: [ic2(2)][win(7)][col(64)][j(8)] ; win = exact 8-partition of 56 staged rows.
__global__ __launch_bounds__(192, 2) void k7m(const u16* __restrict__ inb, const u16* __restrict__ wpk,
                                              const float* __restrict__ b5, u16* __restrict__ y5){
  __shared__ __align__(16) u16 itile[7168];          // 14,336 B
  int bid = blockIdx.x;
  int ocb = bid & 7;
  int rem = bid >> 3;
  int n8  = rem & 7;
  int r   = rem >> 3;                                // 0..7
  int tid = threadIdx.x;
  int w = tid / 64, lane = tid & 63, quad = lane >> 4, m = lane & 15;
  int ic2q = quad >> 1, kyh = quad & 1;

  f32x4 acc[8][6];
  #pragma unroll
  for (int tm=0;tm<8;++tm)
    #pragma unroll
    for (int t=0;t<6;++t) acc[tm][t] = (f32x4){0.f,0.f,0.f,0.f};

  const u16* gin   = inb + ((size_t)n8 * 64) * 4096;       // + ic*4096 + iy*64 + col
  const u16* wblock = wpk + ((size_t)ocb << 21);

  // precompute B-frag LDS offsets (elems) for the 6 n-tiles
  int boff[6];
  #pragma unroll
  for (int t=0;t<6;++t){
    int s = t/3;
    int win = 2*w + s + kyh;
    boff[t] = ((ic2q*7 + win)*64 + (t%3)*16 + m)*8;
  }

  #pragma unroll 1
  for (int chunk=0; chunk<32; ++chunk){
    __syncthreads();
    // stage 2 ic x 56 rows x 64 cols, transposed into [ic2][win][col][j]
    {
      const u16* gq = gin + (size_t)(chunk*2)*4096 + r*64;
      for (int v = tid; v < 1792; v += 192){           // 2 ic x 28 iy-pairs x 32 col-pairs
        int cp  = v & 31;
        int t2  = v >> 5;                              // 0..55
        int iyp = t2 % 28;
        int ic2 = t2 / 28;
        int iy0 = iyp*2;
        const u16* g = gq + ic2*4096 + iy0*64 + 2*cp;
        u32 d0 = *(const u32*)(g);
        u32 d1 = *(const u32*)(g + 64);
        u32 lo = (d0 & 0xffffu) | (d1 << 16);          // col 2cp:   rows iy0, iy0+1
        u32 hi = (d0 >> 16) | (d1 & 0xffff0000u);      // col 2cp+1
        int win = iy0 >> 3, j = iy0 & 7;
        int base = ((ic2*7 + win)*64 + 2*cp)*8 + j;
        *(u32*)&itile[base]     = lo;
        *(u32*)&itile[base + 8] = hi;
      }
    }
    __syncthreads();
    const u16* wchunk = wblock + (chunk << 16);
    #pragma unroll 1
    for (int kx=0; kx<16; ++kx){
      short8 bf[6];
      #pragma unroll
      for (int t=0;t<6;++t)
        bf[t] = *(const short8*)&itile[boff[t] + kx*8]; // col advances with kx: +8 elems
      const u16* wk = wchunk + kx*4096 + quad*1024 + m*8;
      #pragma unroll
      for (int tg=0; tg<2; ++tg){
        short8 af[4];
        #pragma unroll
        for (int q2=0;q2<4;++q2)
          af[q2] = *(const short8*)(wk + (tg*4+q2)*128);   // (+16 oc)*8 elems
        #pragma unroll
        for (int q2=0;q2<4;++q2)
          #pragma unroll
          for (int t=0;t<6;++t)
            acc[tg*4+q2][t] = __builtin_amdgcn_mfma_f32_16x16x32_bf16(af[q2], bf[t], acc[tg*4+q2][t], 0, 0, 0);
      }
    }
  }
  // epilogue: oc = ocb*128 + tm*16 + quad*4 + rr ; px: row = r+16w+8s, ox = (t%3)*16+m
  #pragma unroll
  for (int tm=0;tm<8;++tm){
    #pragma unroll
    for (int rr=0;rr<4;++rr){
      int oc = ocb*128 + tm*16 + quad*4 + rr;
      float bias = b5[oc];
      #pragma unroll
      for (int t=0;t<6;++t){
        int row = r + 16*w + 8*(t/3);
        int ox  = (t%3)*16 + m;
        float v = acc[tm][t][rr] + bias;
        v = v>0.f ? v : 0.f;
        y5[(((size_t)n8*1024 + oc)*48 + row)*48 + ox] = f2bf(v);
      }
    }
  }
}

// ---------------- K8a: 1x1 conv (1024->1024) MFMA + relu + w7-dot + block reduce + atomicAdd
__global__ __launch_bounds__(128) void k8a(const u16* __restrict__ y5, const u16* __restrict__ w6pk,
                                           const float* __restrict__ b6, const float* __restrict__ w7,
                                           float* __restrict__ accum){
  __shared__ __align__(16) u16 btile[96*136];        // 26,112 B
  __shared__ float red[8*96];
  int bid = blockIdx.x;
  int mb = bid & 7;
  int r  = bid >> 3;
  int n8 = r / 24, rp = r % 24;
  int r0 = 2*rp;
  int tid = threadIdx.x;
  int w = tid >> 6, lane = tid & 63, quad = lane >> 4, m = lane & 15;

  f32x4 acc[4][6];
  #pragma unroll
  for (int tm=0;tm<4;++tm)
    #pragma unroll
    for (int t=0;t<6;++t) acc[tm][t] = (f32x4){0.f,0.f,0.f,0.f};

  #pragma unroll 1
  for (int kc=0; kc<8; ++kc){
    __syncthreads();
    for (int u=tid; u<6144; u+=128){                 // 128 ic x 48 px-pairs
      int pp = u % 48; int ic2 = u / 48;
      int rowl = pp / 24; int ox0 = (pp % 24)*2;
      u32 val = *(const u32*)(y5 + (((size_t)(n8*1024 + kc*128 + ic2)*48) + r0 + rowl)*48 + ox0);
      int px = rowl*48 + ox0;
      btile[(px  )*136 + ic2] = (u16)(val & 0xffffu);
      btile[(px+1)*136 + ic2] = (u16)(val >> 16);
    }
    __syncthreads();
    #pragma unroll 1
    for (int kk=0; kk<4; ++kk){
      short8 af[4];
      #pragma unroll
      for (int tm=0;tm<4;++tm)
        af[tm] = *(const short8*)(w6pk + (size_t)(mb*128 + w*64 + tm*16 + m)*1024 + kc*128 + kk*32 + quad*8);
      short8 bf[6];
      #pragma unroll
      for (int t=0;t<6;++t){
        int pxl = ((t>=3)?48:0) + (t%3)*16 + m;
        bf[t] = *(const short8*)(btile + pxl*136 + kk*32 + quad*8);
      }
      #pragma unroll
      for (int tm=0;tm<4;++tm)
        #pragma unroll
        for (int t=0;t<6;++t)
          acc[tm][t] = __builtin_amdgcn_mfma_f32_16x16x32_bf16(af[tm], bf[t], acc[tm][t], 0, 0, 0);
    }
  }
  float part[6];
  #pragma unroll
  for (int t=0;t<6;++t) part[t]=0.f;
  #pragma unroll
  for (int tm=0;tm<4;++tm){
    #pragma unroll
    for (int rr=0;rr<4;++rr){
      int oc = mb*128 + w*64 + tm*16 + quad*4 + rr;
      float bb = b6[oc];
      float ww = w7[oc];
      #pragma unroll
      for (int t=0;t<6;++t){
        float z = acc[tm][t][rr] + bb;
        z = z>0.f ? z : 0.f;
        part[t] += ww*z;
      }
    }
  }
  #pragma unroll
  for (int t=0;t<6;++t){
    int pxl = ((t>=3)?48:0) + (t%3)*16 + m;
    red[(w*4+quad)*96 + pxl] = part[t];
  }
  __syncthreads();
  if (tid < 96){
    float s = 0.f;
    #pragma unroll
    for (int k=0;k<8;++k) s += red[k*96 + tid];
    int rowl = tid / 48, ox = tid % 48;
    atomicAdd(&accum[((size_t)n8*48 + r0 + rowl)*48 + ox], s);
  }
}

// ---------------- K8b: sigmoid + interweave. accum (8,48,48) -> out (2,1,96,96) f32
__global__ __launch_bounds__(256) void k8b(const float* __restrict__ accum, const float* __restrict__ b7,
                                           float* __restrict__ out){
  int idx = blockIdx.x*256 + threadIdx.x;
  if (idx >= 18432) return;
  int n8 = idx / 2304; int rem = idx % 2304;
  int oy = rem / 48, ox = rem % 48;
  float s = accum[idx] + b7[0];
  float sig = 1.f / (1.f + expf(-s));
  int v = n8 >> 1, n = n8 & 1;
  int a = v & 1, bcol = v >> 1;
  out[((size_t)n*96 + 2*oy + a)*96 + 2*ox + bcol] = sig;
}

// ---------------- workspace layout (fp32-element offsets)
// Cb   [0, 1,048,576)           bf16 padded (8,64,64,64) = 2,097,152 u16 (k6 out, k7m in)
//   (pooled C lives at [0, 2,097,152) f32 only between k3..k4; k6 overwrites its first half — C is dead by then)
// A    [2,097,152, 4,194,304)   f32, dead after k5
// B    [4,194,304, 6,291,456)   f32, dead after k6
// F    [2,097,152, 11,534,336)  y5 bf16 (overlaps dead A,B; live k7m->k8a)
// Wpk5 [11,534,336, 19,922,944) bf16 16,777,216
// W6pk [19,922,944, 20,447,232) bf16 1,048,576
// accum[20,447,232, 20,465,664) f32 18,432

extern "C" void kernel_launch(void* const* d_in, const int* in_sizes, int n_in,
                              void* d_out, int out_size, void* d_ws, size_t ws_size,
                              hipStream_t stream){
  const float* x  = (const float*)d_in[0];
  const float* w1 = (const float*)d_in[1];
  const float* b1 = (const float*)d_in[2];
  const float* w2 = (const float*)d_in[3];
  const float* b2 = (const float*)d_in[4];
  const float* w3 = (const float*)d_in[5];
  const float* b3 = (const float*)d_in[6];
  const float* w4 = (const float*)d_in[7];
  const float* b4 = (const float*)d_in[8];
  const float* w5 = (const float*)d_in[9];
  const float* b5 = (const float*)d_in[10];
  const float* w6 = (const float*)d_in[11];
  const float* b6 = (const float*)d_in[12];
  const float* w7 = (const float*)d_in[13];
  const float* b7 = (const float*)d_in[14];
  float* ws = (float*)d_ws;
  float* C  = ws;                       // pooled f32 (k3 out, k4 in)
  u16*   Cb = (u16*)ws;                 // bf16 padded (k6 out, k7m in)
  float* A  = ws + 2097152;
  float* B  = ws + 4194304;
  u16*   F    = (u16*)(ws + 2097152);
  u16*   Wpk5 = (u16*)(ws + 11534336);
  u16*   W6pk = (u16*)(ws + 19922944);
  float* accum = ws + 20447232;
  float* out = (float*)d_out;

  hipLaunchKernelGGL(k0w5,            dim3(65536), dim3(256), 0, stream, w5, Wpk5);
  hipLaunchKernelGGL(k0w6,            dim3(4096),  dim3(256), 0, stream, w6, W6pk);
  hipLaunchKernelGGL(k0z,             dim3(72),    dim3(256), 0, stream, accum);
  hipLaunchKernelGGL(k1_conv7x7,      dim3(8192),  dim3(256), 0, stream, x, w1, b1, A);
  hipLaunchKernelGGL(k2_conv5x5,      dim3(8192),  dim3(256), 0, stream, A, w2, b2, B);
  hipLaunchKernelGGL(k3_lrn_crop_pool,dim3(7938),  dim3(256), 0, stream, B, C);
  hipLaunchKernelGGL(k_conv3x3,       dim3(8192),  dim3(256), 0, stream, C, w3, b3, A);
  hipLaunchKernelGGL(k_conv3x3,       dim3(8192),  dim3(256), 0, stream, A, w4, b4, B);
  hipLaunchKernelGGL(k6_lrn_bf,       dim3(8192),  dim3(256), 0, stream, B, Cb);
  hipLaunchKernelGGL(k7m,             dim3(512),   dim3(192), 0, stream, Cb, Wpk5, b5, F);
  hipLaunchKernelGGL(k8a,             dim3(1536),  dim3(128), 0, stream, F, W6pk, b6, w7, accum);
  hipLaunchKernelGGL(k8b,             dim3(72),    dim3(256), 0, stream, accum, b7, out);
}